// Round 7
// baseline (136.063 us; speedup 1.0000x reference)
//
#include <hip/hip_runtime.h>

#define B_ 16
#define L_ 32
#define O_ 32
#define M_ 256
#define CH_ 544   // L*(P+1)

// ---------- cross-lane helpers ----------

__device__ __forceinline__ float rl(float v, int lane) {
  return __int_as_float(__builtin_amdgcn_readlane(__float_as_int(v), lane));
}

__device__ __forceinline__ float sum16_rl(float v) {
  float s = rl(v, 0);
#pragma unroll
  for (int j = 1; j < 16; j++) s += rl(v, j);
  return s;
}

// force a wave-uniform condition into an SGPR so the compiler emits s_cbranch
__device__ __forceinline__ int uni(int c) { return __builtin_amdgcn_readfirstlane(c); }

__device__ __forceinline__ float frcp(float x) { return __builtin_amdgcn_rcpf(x); }
__device__ __forceinline__ float frsq(float x) { return __builtin_amdgcn_rsqf(x); }

// ---------- LAPACK helper transcriptions (f32, branchless) ----------

__device__ __forceinline__ float slapy2f(float x, float y) {
  float xa = fabsf(x), ya = fabsf(y);
  float w = fmaxf(xa, ya), z = fminf(xa, ya);
  float q = z * frcp(w);
  float res = w * sqrtf(1.f + q * q);
  return (z == 0.f) ? w : res;
}

// LAPACK >= 3.10 slartg convention; single-rsq, branchless.
__device__ __forceinline__ void slartgf(float f, float g, float* c, float* s, float* r) {
  float t = f * f + g * g;
  float inv = frsq(t);
  float d = t * inv;
  float cg_ = fabsf(f) * inv;
  float rg = copysignf(d, f);
  float sg = g * copysignf(inv, f);
  bool g0 = (g == 0.f), f0 = (f == 0.f);
  *c = g0 ? 1.f : (f0 ? 0.f : cg_);
  *s = g0 ? 0.f : (f0 ? copysignf(1.f, g) : sg);
  *r = g0 ? f : (f0 ? fabsf(g) : rg);
}

// returns (rt1, rt2, cs1, sn1); noinline: 1 code copy instead of 4 (icache)
__device__ __noinline__ float4 slaev2f(float a, float b, float c) {
  float sm = a + c, df = a - c;
  float adf = fabsf(df);
  float tb = b + b;
  float ab = fabsf(tb);
  float acmx, acmn;
  if (fabsf(a) > fabsf(c)) { acmx = a; acmn = c; } else { acmx = c; acmn = a; }
  float rt;
  if (adf > ab) { float q = ab / adf; rt = adf * sqrtf(1.f + q * q); }
  else if (adf < ab) { float q = adf / ab; rt = ab * sqrtf(1.f + q * q); }
  else rt = ab * sqrtf(2.f);
  float rt1, rt2;
  int sgn1;
  if (sm < 0.f) { rt1 = 0.5f * (sm - rt); sgn1 = -1; rt2 = (acmx / rt1) * acmn - (b / rt1) * b; }
  else if (sm > 0.f) { rt1 = 0.5f * (sm + rt); sgn1 = 1; rt2 = (acmx / rt1) * acmn - (b / rt1) * b; }
  else { rt1 = 0.5f * rt; rt2 = -0.5f * rt; sgn1 = 1; }
  float cs; int sgn2;
  if (df >= 0.f) { cs = df + rt; sgn2 = 1; } else { cs = df - rt; sgn2 = -1; }
  float acs = fabsf(cs), c1, s1;
  if (acs > ab) { float ct = -tb / cs; s1 = 1.f / sqrtf(1.f + ct * ct); c1 = ct * s1; }
  else if (ab == 0.f) { c1 = 1.f; s1 = 0.f; }
  else { float tn = -cs / tb; c1 = 1.f / sqrtf(1.f + tn * tn); s1 = tn * c1; }
  if (sgn1 == sgn2) { float tn = c1; c1 = -s1; s1 = tn; }
  return make_float4(rt1, rt2, c1, s1);
}

// ---------- Kernel 1: weighted pose second moments (barrier at reduce only) ----------
__global__ __launch_bounds__(256) void moments_kernel(const float* __restrict__ in,
                                                      float* __restrict__ Tmom) {
  int bl = blockIdx.x;
  int b = bl >> 5, l = bl & 31;
  int t = threadIdx.x;
  int w = t >> 6, lane = t & 63;
  __shared__ __align__(16) float ut[4][16][68];
  __shared__ float red[4][16][16];
  const float* base = in + (size_t)b * (M_ * CH_);
  const float* row = base + (size_t)(w * 64 + lane) * CH_ + l * 16;
  float4 p0 = *(const float4*)(row + 0);
  float4 p1 = *(const float4*)(row + 4);
  float4 p2 = *(const float4*)(row + 8);
  float4 p3 = *(const float4*)(row + 12);
  float a = row[512 - l * 16 + l];
  float (*u)[68] = ut[w];
  u[0][lane] = a * p0.x;  u[1][lane] = a * p0.y;  u[2][lane] = a * p0.z;  u[3][lane] = a * p0.w;
  u[4][lane] = a * p1.x;  u[5][lane] = a * p1.y;  u[6][lane] = a * p1.z;  u[7][lane] = a * p1.w;
  u[8][lane] = a * p2.x;  u[9][lane] = a * p2.y;  u[10][lane] = a * p2.z; u[11][lane] = a * p2.w;
  u[12][lane] = a * p3.x; u[13][lane] = a * p3.y; u[14][lane] = a * p3.z; u[15][lane] = a * p3.w;
  asm volatile("" ::: "memory");
  int c = lane & 15, r0 = lane >> 4;
  float acc0 = 0.f, acc1 = 0.f, acc2 = 0.f, acc3 = 0.f;
#pragma unroll
  for (int m4 = 0; m4 < 64; m4 += 4) {
    float4 cv = *(const float4*)&u[c][m4];
    float4 a0 = *(const float4*)&u[r0][m4];
    float4 a1 = *(const float4*)&u[r0 + 4][m4];
    float4 a2 = *(const float4*)&u[r0 + 8][m4];
    float4 a3 = *(const float4*)&u[r0 + 12][m4];
    acc0 += a0.x * cv.x + a0.y * cv.y + a0.z * cv.z + a0.w * cv.w;
    acc1 += a1.x * cv.x + a1.y * cv.y + a1.z * cv.z + a1.w * cv.w;
    acc2 += a2.x * cv.x + a2.y * cv.y + a2.z * cv.z + a2.w * cv.w;
    acc3 += a3.x * cv.x + a3.y * cv.y + a3.z * cv.z + a3.w * cv.w;
  }
  red[w][r0][c] = acc0;
  red[w][r0 + 4][c] = acc1;
  red[w][r0 + 8][c] = acc2;
  red[w][r0 + 12][c] = acc3;
  __syncthreads();
  int rr_ = t >> 4, cc_ = t & 15;
  float s = (red[0][rr_][cc_] + red[1][rr_][cc_]) + (red[2][rr_][cc_] + red[3][rr_][cc_]);
  Tmom[bl * 256 + t] = s;
}

// ---------- Kernel 2: gram + register-resident LAPACK-replica eigh ----------
__global__ __launch_bounds__(64) void gram_eig_kernel(const float* __restrict__ Tmom,
                                                      const float* __restrict__ Wt,
                                                      const float* __restrict__ bias,
                                                      float* __restrict__ out) {
  int bo = blockIdx.x;
  int b = bo >> 5, o = bo & 31;
  int lane = threadIdx.x;

  __shared__ __align__(16) float4 Wall4[128];
  __shared__ __align__(16) float4 Tall4[32 * 72];   // [l][i_*18 + jj*4 + i2], 36 KB
  __shared__ float A[16][17];
  __shared__ __align__(16) float Zt[16][16];

  float biasv = bias[o];

  // ---- stage W + ALL 32 T-tiles into LDS once (single wave, DS in-order) ----
  const float4* Wt4 = (const float4*)Wt;
#pragma unroll
  for (int k = 0; k < 2; k++) {
    int idx = lane + 64 * k;
    int l = idx >> 2, part = idx & 3;
    Wall4[idx] = Wt4[(l * 32 + o) * 4 + part];
  }
  const float4* T4 = (const float4*)(Tmom + (size_t)(b * 32) * 256);
  int soff = (lane >> 4) * 18 + (lane & 15);
#pragma unroll
  for (int l = 0; l < 32; l++) {
    Tall4[l * 72 + soff] = T4[l * 64 + lane];
  }
  asm volatile("" ::: "memory");

  // ---- gram: barrier-free, pure LDS reads (pipelineable) ----
  int p = lane >> 2;
  int i_ = p >> 2, k_ = p & 3;
  int i2 = lane & 3;
  float gx = 0.f, gy = 0.f, gz = 0.f, gw = 0.f;
  const float* WallF = (const float*)Wall4;
  for (int l = 0; l < 32; l++) {
    float4 wq0 = Wall4[l * 4 + 0], wq1 = Wall4[l * 4 + 1];
    float4 wq2 = Wall4[l * 4 + 2], wq3 = Wall4[l * 4 + 3];
#pragma unroll
    for (int jj = 0; jj < 4; jj++) {
      float4 trow = Tall4[l * 72 + i_ * 18 + jj * 4 + i2];
      float ux = trow.x * wq0.x + trow.y * wq1.x + trow.z * wq2.x + trow.w * wq3.x;
      float uy = trow.x * wq0.y + trow.y * wq1.y + trow.z * wq2.y + trow.w * wq3.y;
      float uz = trow.x * wq0.z + trow.y * wq1.z + trow.z * wq2.z + trow.w * wq3.z;
      float uw = trow.x * wq0.w + trow.y * wq1.w + trow.z * wq2.w + trow.w * wq3.w;
      float wk = WallF[l * 16 + jj * 4 + k_];
      gx += wk * ux; gy += wk * uy; gz += wk * uz; gw += wk * uw;
    }
  }
  {
    int q0 = i2 * 4;
    A[p][q0 + 0] = gx; A[p][q0 + 1] = gy; A[p][q0 + 2] = gz; A[p][q0 + 3] = gw;
  }
  asm volatile("" ::: "memory");

  // ---- load A columns into registers: lane c holds a[r] = A[r][c] ----
  int c16 = lane & 15;
  float a[16];
#pragma unroll
  for (int r = 0; r < 16; r++) a[r] = A[r][c16];

  float trace;
  {
    float diag = 0.f;
#pragma unroll
    for (int r = 0; r < 16; r++) if (c16 == r) diag = a[r];
    trace = sum16_rl((lane < 16) ? diag : 0.f);
  }

  // ---- ssytd2 (lower), register-resident ----
  float dreg = 0.f, ereg = 0.f, taureg = 0.f;
  float hv[14];
#pragma unroll
  for (int i = 0; i < 15; i++) {
    float cn = 0.f;
#pragma unroll
    for (int r = i + 2; r < 16; r++) cn += a[r] * a[r];
    float xn2 = rl(cn, i);
    float alpha = rl(a[i + 1], i);
    float taui = 0.f;
    float vc = 0.f;
    if (uni(xn2 == 0.f ? 1 : 0)) {
      if (lane == i) ereg = alpha;
    } else {
      float xnorm = sqrtf(xn2);
      float beta = -copysignf(slapy2f(alpha, xnorm), alpha);
      taui = (beta - alpha) / beta;
      float rs = 1.f / (alpha - beta);
      if (lane == i) ereg = beta;
      vc = (lane == i + 1) ? 1.f : ((lane >= i + 2 && lane < 16) ? a[i] * rs : 0.f);
      float vb[16];
#pragma unroll
      for (int r = i + 1; r < 16; r++) vb[r] = rl(vc, r);
      float acc = 0.f;
#pragma unroll
      for (int r = i + 1; r < 16; r++) acc += a[r] * vb[r];
      float wc = (lane >= i + 1 && lane < 16) ? taui * acc : 0.f;
      float wb[16];
#pragma unroll
      for (int r = i + 1; r < 16; r++) wb[r] = rl(wc, r);
      float dot = 0.f;
#pragma unroll
      for (int r = i + 1; r < 16; r++) dot += vb[r] * wb[r];
      float alph2 = -0.5f * taui * dot;
      wc += alph2 * vc;
#pragma unroll
      for (int r = i + 1; r < 16; r++) wb[r] += alph2 * vb[r];
#pragma unroll
      for (int r = i + 1; r < 16; r++) a[r] -= vb[r] * wc + wb[r] * vc;
    }
    if (i < 14) hv[i] = vc;
    if (lane == i) taureg = taui;
  }
#pragma unroll
  for (int r = 0; r < 16; r++) if (c16 == r) dreg = a[r];
  if (lane >= 16) dreg = 0.f;

  // ---- form Q = H(1)..H(14); lane = column, rows in registers ----
  float z[16];
#pragma unroll
  for (int r = 0; r < 16; r++) z[r] = (lane == r) ? 1.f : 0.f;
#pragma unroll
  for (int i = 13; i >= 0; i--) {
    float taui = rl(taureg, i);
    if (uni(taui != 0.f ? 1 : 0)) {
      float vbq[16];
      float s = 0.f;
#pragma unroll
      for (int r = i + 1; r < 16; r++) { vbq[r] = rl(hv[i], r); s += vbq[r] * z[r]; }
      s *= taui;
#pragma unroll
      for (int r = i + 1; r < 16; r++) z[r] -= vbq[r] * s;
    }
  }
  if (lane < 16) {
    float4* zt4 = (float4*)&Zt[lane][0];      // Zt[col][row]
    zt4[0] = make_float4(z[0], z[1], z[2], z[3]);
    zt4[1] = make_float4(z[4], z[5], z[6], z[7]);
    zt4[2] = make_float4(z[8], z[9], z[10], z[11]);
    zt4[3] = make_float4(z[12], z[13], z[14], z[15]);
  }
  asm volatile("" ::: "memory");

  // ---- transpose handoff: zz[col] = Z[lane][col], register-resident ----
  float zz[16];
#pragma unroll
  for (int k2 = 0; k2 < 16; k2++) zz[k2] = Zt[k2][c16];

  // ---- ssteqr; d,e lane-resident; Z in registers; forced scalar branches ----
  const float eps = 5.9604645e-08f;
  const float eps2 = eps * eps;
  const float safmin = 1.17549435e-38f;
  int l1 = 0, jtot = 0;
  const int nmaxit = 480;
  float dsh = __shfl(dreg, (lane + 1) & 63, 64);

  while (uni(l1 < 16 ? 1 : 0)) {
    if (l1 > 0) { if (lane == l1 - 1) ereg = 0.f; }
    bool co = (lane < 15) &&
              ((ereg == 0.f) ||
               (fabsf(ereg) <= __builtin_amdgcn_sqrtf(fabsf(dreg)) *
                                   __builtin_amdgcn_sqrtf(fabsf(dsh)) * eps));
    unsigned long long bm = __ballot(co) & ~((1ull << l1) - 1ull);
    int m = bm ? (__ffsll(bm) - 1) : 15;
    if (m < 15) { if (lane == m) ereg = 0.f; }
    int l = l1, lend = m;
    l1 = m + 1;
    if (uni(lend == l ? 1 : 0)) continue;
    {
      float dl = rl(dreg, l), dle = rl(dreg, lend);
      if (fabsf(dle) < fabsf(dl)) { int tq = l; l = lend; lend = tq; }
    }

    if (uni(lend > l ? 1 : 0)) {
      // ---- QL ----
      for (;;) {
        bool cj = (lane < 15) && ((ereg * ereg) <= eps2 * fabsf(dreg) * fabsf(dsh) + safmin);
        int mq;
        if (l != lend) {
          unsigned long long bb2 = __ballot(cj) & ((1ull << lend) - 1ull) & ~((1ull << l) - 1ull);
          mq = bb2 ? (__ffsll(bb2) - 1) : lend;
        } else mq = lend;
        if (mq < lend) { if (lane == mq) ereg = 0.f; }
        if (uni(mq == l ? 1 : 0)) { l++; if (uni(l <= lend ? 1 : 0)) continue; break; }
        if (uni(mq == l + 1 ? 1 : 0)) {
          float4 ev = slaev2f(rl(dreg, l), rl(ereg, l), rl(dreg, l + 1));
          float rt1 = ev.x, rt2 = ev.y, cc = ev.z, ss = ev.w;
#pragma unroll
          for (int k = 0; k < 15; k++) if (uni(k == l ? 1 : 0)) {
            float z1 = zz[k + 1], z0v = zz[k];
            zz[k + 1] = cc * z1 - ss * z0v;
            zz[k] = ss * z1 + cc * z0v;
          }
          if (lane == l) { dreg = rt1; ereg = 0.f; dsh = rt2; }
          if (lane == l + 1) dreg = rt2;
          if (lane == l - 1) dsh = rt1;
          l += 2; if (uni(l <= lend ? 1 : 0)) continue; break;
        }
        if (uni(jtot == nmaxit ? 1 : 0)) break;
        jtot++;
        float d0 = dreg, e0 = ereg;   // pre-sweep snapshots
        float pp = rl(d0, l);
        float e_lv = rl(e0, l);
        float gg = (rl(d0, l + 1) - pp) * 0.5f * frcp(e_lv);
        float rr = slapy2f(gg, 1.f);
        gg = rl(d0, mq) - pp + e_lv * frcp(gg + copysignf(rr, gg));
        float ss_ = 1.f, cc_ = 1.f;
        pp = 0.f;
#pragma unroll
        for (int i = 14; i >= 0; i--) {
          if (uni((i <= mq - 1 && i >= l) ? 1 : 0)) {   // scalar branch, i compile-time
            float e_i = rl(e0, i), d_i = rl(d0, i), d_i1 = rl(d0, i + 1);
            float ff = ss_ * e_i, bb = cc_ * e_i;
            slartgf(gg, ff, &cc_, &ss_, &rr);
            if (i != mq - 1) { if (lane == i + 1) ereg = rr; }
            gg = d_i1 - pp;
            rr = (d_i - gg) * ss_ + 2.f * cc_ * bb;
            pp = ss_ * rr;
            float dnew = gg + pp;
            if (lane == i + 1) dreg = dnew;
            if (lane == i) dsh = dnew;
            gg = cc_ * rr - bb;
            float z1 = zz[i + 1], z0v = zz[i];   // QL (slasr 'B', (c,-s))
            zz[i + 1] = cc_ * z1 + ss_ * z0v;
            zz[i] = -ss_ * z1 + cc_ * z0v;
          }
        }
        float dlv = rl(d0, l) - pp;
        if (lane == l) { dreg = dlv; ereg = gg; }
        if (lane == l - 1) dsh = dlv;
      }
    } else {
      // ---- QR ----
      for (;;) {
        bool cj = (lane < 15) && ((ereg * ereg) <= eps2 * fabsf(dreg) * fabsf(dsh) + safmin);
        int mq;
        if (l != lend) {
          unsigned long long bb2 = __ballot(cj) & ((1ull << l) - 1ull) & ~((1ull << lend) - 1ull);
          mq = bb2 ? (63 - __clzll(bb2) + 1) : lend;
        } else mq = lend;
        if (mq > lend) { if (lane == mq - 1) ereg = 0.f; }
        if (uni(mq == l ? 1 : 0)) { l--; if (uni(l >= lend ? 1 : 0)) continue; break; }
        if (uni(mq == l - 1 ? 1 : 0)) {
          float4 ev = slaev2f(rl(dreg, l - 1), rl(ereg, l - 1), rl(dreg, l));
          float rt1 = ev.x, rt2 = ev.y, cc = ev.z, ss = ev.w;
#pragma unroll
          for (int k = 0; k < 15; k++) if (uni(k == l - 1 ? 1 : 0)) {
            float z1 = zz[k + 1], z0v = zz[k];
            zz[k + 1] = cc * z1 - ss * z0v;
            zz[k] = ss * z1 + cc * z0v;
          }
          if (lane == l - 1) { dreg = rt1; ereg = 0.f; dsh = rt2; }
          if (lane == l) dreg = rt2;
          if (lane == l - 2) dsh = rt1;
          l -= 2; if (uni(l >= lend ? 1 : 0)) continue; break;
        }
        if (uni(jtot == nmaxit ? 1 : 0)) break;
        jtot++;
        float d0 = dreg, e0 = ereg;
        float pp = rl(d0, l);
        float e_lm1 = rl(e0, l - 1);
        float gg = (rl(d0, l - 1) - pp) * 0.5f * frcp(e_lm1);
        float rr = slapy2f(gg, 1.f);
        gg = rl(d0, mq) - pp + e_lm1 * frcp(gg + copysignf(rr, gg));
        float ss_ = 1.f, cc_ = 1.f;
        pp = 0.f;
#pragma unroll
        for (int i = 0; i <= 14; i++) {
          if (uni((i >= mq && i <= l - 1) ? 1 : 0)) {   // scalar branch, i compile-time
            float e_i = rl(e0, i), d_i = rl(d0, i), d_i1 = rl(d0, i + 1);
            float ff = ss_ * e_i, bb = cc_ * e_i;
            slartgf(gg, ff, &cc_, &ss_, &rr);
            if (i != mq) { if (lane == i - 1) ereg = rr; }
            gg = d_i - pp;
            rr = (d_i1 - gg) * ss_ + 2.f * cc_ * bb;
            pp = ss_ * rr;
            float dnew = gg + pp;
            if (lane == i) dreg = dnew;
            if (lane == i - 1) dsh = dnew;
            gg = cc_ * rr - bb;
            float z1 = zz[i + 1], z0v = zz[i];   // QR (slasr 'F', (c,s))
            zz[i + 1] = cc_ * z1 - ss_ * z0v;
            zz[i] = ss_ * z1 + cc_ * z0v;
          }
        }
        float dlv = rl(d0, l) - pp;
        if (lane == l) dreg = dlv;
        if (lane == l - 1) { ereg = gg; dsh = dlv; }
      }
    }
  }

  // ---- outputs ----
  float mx = rl(dreg, 0);
  int k = 0;
#pragma unroll
  for (int j = 1; j < 16; j++) {
    float dj = rl(dreg, j);
    if (dj > mx) { mx = dj; k = j; }
  }
  float ratio = mx / trace;
  float act = 1.f / (1.f + expf(-(ratio - biasv)));
  float zk = zz[0];
#pragma unroll
  for (int j = 1; j < 16; j++) zk = (k == j) ? zz[j] : zk;
  if (lane < 16) out[512 + bo * 16 + lane] = zk;
  if (lane == 0) out[bo] = act;
}

extern "C" void kernel_launch(void* const* d_in, const int* in_sizes, int n_in,
                              void* d_out, int out_size, void* d_ws, size_t ws_size,
                              hipStream_t stream) {
  const float* in = (const float*)d_in[0];
  const float* w = (const float*)d_in[1];
  const float* bias = (const float*)d_in[2];
  float* out = (float*)d_out;
  float* Tmom = (float*)d_ws;  // 512 * 256 floats = 512 KB scratch

  moments_kernel<<<B_ * L_, 256, 0, stream>>>(in, Tmom);
  gram_eig_kernel<<<B_ * O_, 64, 0, stream>>>(Tmom, w, bias, out);
}

// Round 8
// 135.045 us; speedup vs baseline: 1.0075x; 1.0075x over previous
//
#include <hip/hip_runtime.h>

#define B_ 16
#define L_ 32
#define O_ 32
#define M_ 256
#define CH_ 544   // L*(P+1)
#define WS2_STRIDE 320   // per-bo handoff floats: 256 Z + 16 d + 15 e + 1 trace (+pad)

// ---------- cross-lane helpers ----------

__device__ __forceinline__ float rl(float v, int lane) {
  return __int_as_float(__builtin_amdgcn_readlane(__float_as_int(v), lane));
}

__device__ __forceinline__ float sum16_rl(float v) {
  float s = rl(v, 0);
#pragma unroll
  for (int j = 1; j < 16; j++) s += rl(v, j);
  return s;
}

__device__ __forceinline__ float frcp(float x) { return __builtin_amdgcn_rcpf(x); }
__device__ __forceinline__ float frsq(float x) { return __builtin_amdgcn_rsqf(x); }

// ---------- LAPACK helper transcriptions (f32) ----------

__device__ __forceinline__ float slapy2f(float x, float y) {
  float xa = fabsf(x), ya = fabsf(y);
  float w = fmaxf(xa, ya), z = fminf(xa, ya);
  float q = z * frcp(w);
  float res = w * sqrtf(1.f + q * q);
  return (z == 0.f) ? w : res;
}

// LAPACK >= 3.10 slartg convention; single-rsq, branchless.
__device__ __forceinline__ void slartgf(float f, float g, float* c, float* s, float* r) {
  float t = f * f + g * g;
  float inv = frsq(t);
  float d = t * inv;
  float cg_ = fabsf(f) * inv;
  float rg = copysignf(d, f);
  float sg = g * copysignf(inv, f);
  bool g0 = (g == 0.f), f0 = (f == 0.f);
  *c = g0 ? 1.f : (f0 ? 0.f : cg_);
  *s = g0 ? 0.f : (f0 ? copysignf(1.f, g) : sg);
  *r = g0 ? f : (f0 ? fabsf(g) : rg);
}

// returns (rt1, rt2, cs1, sn1); noinline: 1 code copy (icache)
__device__ __noinline__ float4 slaev2f(float a, float b, float c) {
  float sm = a + c, df = a - c;
  float adf = fabsf(df);
  float tb = b + b;
  float ab = fabsf(tb);
  float acmx, acmn;
  if (fabsf(a) > fabsf(c)) { acmx = a; acmn = c; } else { acmx = c; acmn = a; }
  float rt;
  if (adf > ab) { float q = ab / adf; rt = adf * sqrtf(1.f + q * q); }
  else if (adf < ab) { float q = adf / ab; rt = ab * sqrtf(1.f + q * q); }
  else rt = ab * sqrtf(2.f);
  float rt1, rt2;
  int sgn1;
  if (sm < 0.f) { rt1 = 0.5f * (sm - rt); sgn1 = -1; rt2 = (acmx / rt1) * acmn - (b / rt1) * b; }
  else if (sm > 0.f) { rt1 = 0.5f * (sm + rt); sgn1 = 1; rt2 = (acmx / rt1) * acmn - (b / rt1) * b; }
  else { rt1 = 0.5f * rt; rt2 = -0.5f * rt; sgn1 = 1; }
  float cs; int sgn2;
  if (df >= 0.f) { cs = df + rt; sgn2 = 1; } else { cs = df - rt; sgn2 = -1; }
  float acs = fabsf(cs), c1, s1;
  if (acs > ab) { float ct = -tb / cs; s1 = 1.f / sqrtf(1.f + ct * ct); c1 = ct * s1; }
  else if (ab == 0.f) { c1 = 1.f; s1 = 0.f; }
  else { float tn = -cs / tb; c1 = 1.f / sqrtf(1.f + tn * tn); s1 = tn * c1; }
  if (sgn1 == sgn2) { float tn = c1; c1 = -s1; s1 = tn; }
  return make_float4(rt1, rt2, c1, s1);
}

// ---------- Kernel 1: weighted pose second moments ----------
__global__ __launch_bounds__(256) void moments_kernel(const float* __restrict__ in,
                                                      float* __restrict__ Tmom) {
  int bl = blockIdx.x;
  int b = bl >> 5, l = bl & 31;
  int t = threadIdx.x;
  int w = t >> 6, lane = t & 63;
  __shared__ __align__(16) float ut[4][16][68];
  __shared__ float red[4][16][16];
  const float* base = in + (size_t)b * (M_ * CH_);
  const float* row = base + (size_t)(w * 64 + lane) * CH_ + l * 16;
  float4 p0 = *(const float4*)(row + 0);
  float4 p1 = *(const float4*)(row + 4);
  float4 p2 = *(const float4*)(row + 8);
  float4 p3 = *(const float4*)(row + 12);
  float a = row[512 - l * 16 + l];
  float (*u)[68] = ut[w];
  u[0][lane] = a * p0.x;  u[1][lane] = a * p0.y;  u[2][lane] = a * p0.z;  u[3][lane] = a * p0.w;
  u[4][lane] = a * p1.x;  u[5][lane] = a * p1.y;  u[6][lane] = a * p1.z;  u[7][lane] = a * p1.w;
  u[8][lane] = a * p2.x;  u[9][lane] = a * p2.y;  u[10][lane] = a * p2.z; u[11][lane] = a * p2.w;
  u[12][lane] = a * p3.x; u[13][lane] = a * p3.y; u[14][lane] = a * p3.z; u[15][lane] = a * p3.w;
  asm volatile("" ::: "memory");
  int c = lane & 15, r0 = lane >> 4;
  float acc0 = 0.f, acc1 = 0.f, acc2 = 0.f, acc3 = 0.f;
#pragma unroll
  for (int m4 = 0; m4 < 64; m4 += 4) {
    float4 cv = *(const float4*)&u[c][m4];
    float4 a0 = *(const float4*)&u[r0][m4];
    float4 a1 = *(const float4*)&u[r0 + 4][m4];
    float4 a2 = *(const float4*)&u[r0 + 8][m4];
    float4 a3 = *(const float4*)&u[r0 + 12][m4];
    acc0 += a0.x * cv.x + a0.y * cv.y + a0.z * cv.z + a0.w * cv.w;
    acc1 += a1.x * cv.x + a1.y * cv.y + a1.z * cv.z + a1.w * cv.w;
    acc2 += a2.x * cv.x + a2.y * cv.y + a2.z * cv.z + a2.w * cv.w;
    acc3 += a3.x * cv.x + a3.y * cv.y + a3.z * cv.z + a3.w * cv.w;
  }
  red[w][r0][c] = acc0;
  red[w][r0 + 4][c] = acc1;
  red[w][r0 + 8][c] = acc2;
  red[w][r0 + 12][c] = acc3;
  __syncthreads();
  int rr_ = t >> 4, cc_ = t & 15;
  float s = (red[0][rr_][cc_] + red[1][rr_][cc_]) + (red[2][rr_][cc_] + red[3][rr_][cc_]);
  Tmom[bl * 256 + t] = s;
}

// ---------- Kernel 2a: gram + sytd2 + Q-form; writes Z/d/e/trace to ws2 ----------
__global__ __launch_bounds__(64) void gram_sytd2_kernel(const float* __restrict__ Tmom,
                                                        const float* __restrict__ Wt,
                                                        float* __restrict__ ws2) {
  int bo = blockIdx.x;
  int b = bo >> 5, o = bo & 31;
  int lane = threadIdx.x;

  __shared__ __align__(16) float4 Wall4[128];
  __shared__ __align__(16) float4 Tsh4[4 * 18];
  __shared__ float A[16][17];

  // ---- stage W (single wave: DS in-order, no barrier) ----
  const float4* Wt4 = (const float4*)Wt;
#pragma unroll
  for (int k = 0; k < 2; k++) {
    int idx = lane + 64 * k;
    int l = idx >> 2, part = idx & 3;
    Wall4[idx] = Wt4[(l * 32 + o) * 4 + part];
  }
  asm volatile("" ::: "memory");

  // ---- gram (single-copy T, depth-4 prefetch, barrier-free) ----
  int p = lane >> 2;
  int i_ = p >> 2, k_ = p & 3;
  int i2 = lane & 3;
  float gx = 0.f, gy = 0.f, gz = 0.f, gw = 0.f;
  const float4* T4 = (const float4*)(Tmom + (size_t)(b * 32) * 256);
  const float* WallF = (const float*)Wall4;
  float4 t0 = T4[0 * 64 + lane], t1 = T4[1 * 64 + lane];
  float4 t2 = T4[2 * 64 + lane], t3 = T4[3 * 64 + lane];
  for (int l = 0; l < 32; l++) {
    Tsh4[(lane >> 4) * 18 + (lane & 15)] = t0;
    asm volatile("" ::: "memory");
    t0 = t1; t1 = t2; t2 = t3;
    if (l + 4 < 32) t3 = T4[(l + 4) * 64 + lane];
    float4 wq0 = Wall4[l * 4 + 0], wq1 = Wall4[l * 4 + 1];
    float4 wq2 = Wall4[l * 4 + 2], wq3 = Wall4[l * 4 + 3];
#pragma unroll
    for (int jj = 0; jj < 4; jj++) {
      float4 trow = Tsh4[i_ * 18 + jj * 4 + i2];
      float ux = trow.x * wq0.x + trow.y * wq1.x + trow.z * wq2.x + trow.w * wq3.x;
      float uy = trow.x * wq0.y + trow.y * wq1.y + trow.z * wq2.y + trow.w * wq3.y;
      float uz = trow.x * wq0.z + trow.y * wq1.z + trow.z * wq2.z + trow.w * wq3.z;
      float uw = trow.x * wq0.w + trow.y * wq1.w + trow.z * wq2.w + trow.w * wq3.w;
      float wk = WallF[l * 16 + jj * 4 + k_];
      gx += wk * ux; gy += wk * uy; gz += wk * uz; gw += wk * uw;
    }
    asm volatile("" ::: "memory");
  }
  {
    int q0 = i2 * 4;
    A[p][q0 + 0] = gx; A[p][q0 + 1] = gy; A[p][q0 + 2] = gz; A[p][q0 + 3] = gw;
  }
  asm volatile("" ::: "memory");

  // ---- load A columns into registers: lane c holds a[r] = A[r][c] ----
  int c16 = lane & 15;
  float a[16];
#pragma unroll
  for (int r = 0; r < 16; r++) a[r] = A[r][c16];

  float trace;
  {
    float diag = 0.f;
#pragma unroll
    for (int r = 0; r < 16; r++) if (c16 == r) diag = a[r];
    trace = sum16_rl((lane < 16) ? diag : 0.f);
  }

  // ---- ssytd2 (lower), register-resident ----
  float dreg = 0.f, ereg = 0.f, taureg = 0.f;
  float hv[14];
#pragma unroll
  for (int i = 0; i < 15; i++) {
    float cn = 0.f;
#pragma unroll
    for (int r = i + 2; r < 16; r++) cn += a[r] * a[r];
    float xn2 = rl(cn, i);
    float alpha = rl(a[i + 1], i);
    float taui = 0.f;
    float vc = 0.f;
    if (xn2 == 0.f) {
      if (lane == i) ereg = alpha;
    } else {
      float xnorm = sqrtf(xn2);
      float beta = -copysignf(slapy2f(alpha, xnorm), alpha);
      taui = (beta - alpha) / beta;
      float rs = 1.f / (alpha - beta);
      if (lane == i) ereg = beta;
      vc = (lane == i + 1) ? 1.f : ((lane >= i + 2 && lane < 16) ? a[i] * rs : 0.f);
      float vb[16];
#pragma unroll
      for (int r = i + 1; r < 16; r++) vb[r] = rl(vc, r);
      float acc = 0.f;
#pragma unroll
      for (int r = i + 1; r < 16; r++) acc += a[r] * vb[r];
      float wc = (lane >= i + 1 && lane < 16) ? taui * acc : 0.f;
      float wb[16];
#pragma unroll
      for (int r = i + 1; r < 16; r++) wb[r] = rl(wc, r);
      float dot = 0.f;
#pragma unroll
      for (int r = i + 1; r < 16; r++) dot += vb[r] * wb[r];
      float alph2 = -0.5f * taui * dot;
      wc += alph2 * vc;
#pragma unroll
      for (int r = i + 1; r < 16; r++) wb[r] += alph2 * vb[r];
#pragma unroll
      for (int r = i + 1; r < 16; r++) a[r] -= vb[r] * wc + wb[r] * vc;
    }
    if (i < 14) hv[i] = vc;
    if (lane == i) taureg = taui;
  }
#pragma unroll
  for (int r = 0; r < 16; r++) if (c16 == r) dreg = a[r];
  if (lane >= 16) dreg = 0.f;

  // ---- form Q = H(1)..H(14); lane = column, rows in registers ----
  float z[16];
#pragma unroll
  for (int r = 0; r < 16; r++) z[r] = (lane == r) ? 1.f : 0.f;
#pragma unroll
  for (int i = 13; i >= 0; i--) {
    float taui = rl(taureg, i);
    if (taui != 0.f) {
      float vbq[16];
      float s = 0.f;
#pragma unroll
      for (int r = i + 1; r < 16; r++) { vbq[r] = rl(hv[i], r); s += vbq[r] * z[r]; }
      s *= taui;
#pragma unroll
      for (int r = i + 1; r < 16; r++) z[r] -= vbq[r] * s;
    }
  }

  // ---- handoff: [0..255] Z (col-major: [col*16+row]), [256..271] d, [272..286] e, [288] trace ----
  float* basep = ws2 + (size_t)bo * WS2_STRIDE;
  if (lane < 16) {
    float4* dst = (float4*)(basep + lane * 16);
    dst[0] = make_float4(z[0], z[1], z[2], z[3]);
    dst[1] = make_float4(z[4], z[5], z[6], z[7]);
    dst[2] = make_float4(z[8], z[9], z[10], z[11]);
    dst[3] = make_float4(z[12], z[13], z[14], z[15]);
    basep[256 + lane] = dreg;
  }
  if (lane < 15) basep[272 + lane] = ereg;
  if (lane == 0) basep[288] = trace;
}

// ---------- Kernel 2b: steqr (QL/QR implicit) + outputs ----------
__global__ __launch_bounds__(64) void steqr_kernel(const float* __restrict__ ws2,
                                                   const float* __restrict__ bias,
                                                   float* __restrict__ out) {
  int bo = blockIdx.x;
  int o = bo & 31;
  int lane = threadIdx.x;
  int c16 = lane & 15;
  const float* basep = ws2 + (size_t)bo * WS2_STRIDE;

  float biasv = bias[o];
  float trace = basep[288];
  float zz[16];
#pragma unroll
  for (int k = 0; k < 16; k++) zz[k] = (lane < 16) ? basep[k * 16 + c16] : 0.f;
  float dreg = (lane < 16) ? basep[256 + lane] : 0.f;
  float ereg = (lane < 15) ? basep[272 + lane] : 0.f;
  float dsh = (lane < 15) ? basep[256 + lane + 1] : 0.f;

  const float eps = 5.9604645e-08f;
  const float eps2 = eps * eps;
  const float safmin = 1.17549435e-38f;
  int l1 = 0, jtot = 0;
  const int nmaxit = 480;

  while (l1 < 16) {
    if (l1 > 0) { if (lane == l1 - 1) ereg = 0.f; }
    bool co = (lane < 15) &&
              ((ereg == 0.f) ||
               (fabsf(ereg) <= __builtin_amdgcn_sqrtf(fabsf(dreg)) *
                                   __builtin_amdgcn_sqrtf(fabsf(dsh)) * eps));
    unsigned long long bm = __ballot(co) & ~((1ull << l1) - 1ull);
    int m = bm ? (__ffsll(bm) - 1) : 15;
    if (m < 15) { if (lane == m) ereg = 0.f; }
    int l = l1, lend = m;
    l1 = m + 1;
    if (lend == l) continue;
    {
      float dl = rl(dreg, l), dle = rl(dreg, lend);
      if (fabsf(dle) < fabsf(dl)) { int tq = l; l = lend; lend = tq; }
    }

    if (lend > l) {
      // ---- QL ----
      for (;;) {
        bool cj = (lane < 15) && ((ereg * ereg) <= eps2 * fabsf(dreg) * fabsf(dsh) + safmin);
        int mq;
        if (l != lend) {
          unsigned long long bb2 = __ballot(cj) & ((1ull << lend) - 1ull) & ~((1ull << l) - 1ull);
          mq = bb2 ? (__ffsll(bb2) - 1) : lend;
        } else mq = lend;
        if (mq < lend) { if (lane == mq) ereg = 0.f; }
        if (mq == l) { l++; if (l <= lend) continue; break; }
        if (mq == l + 1) {
          float4 ev = slaev2f(rl(dreg, l), rl(ereg, l), rl(dreg, l + 1));
          float rt1 = ev.x, rt2 = ev.y, cc = ev.z, ss = ev.w;
#pragma unroll
          for (int k = 0; k < 15; k++) if (k == l) {
            float z1 = zz[k + 1], z0v = zz[k];
            zz[k + 1] = cc * z1 - ss * z0v;
            zz[k] = ss * z1 + cc * z0v;
          }
          if (lane == l) { dreg = rt1; ereg = 0.f; dsh = rt2; }
          if (lane == l + 1) dreg = rt2;
          if (lane == l - 1) dsh = rt1;
          l += 2; if (l <= lend) continue; break;
        }
        if (jtot == nmaxit) break;
        jtot++;
        float d0 = dreg, e0 = ereg;   // pre-sweep snapshots
        // hoisted snapshot broadcasts (compile-time indexed, off the chain)
        float dArr[16], eArr[15];
#pragma unroll
        for (int r = 0; r < 16; r++) dArr[r] = rl(d0, r);
#pragma unroll
        for (int r = 0; r < 15; r++) eArr[r] = rl(e0, r);
        float pp = rl(d0, l);
        float e_lv = rl(e0, l);
        float gg = (rl(d0, l + 1) - pp) * 0.5f * frcp(e_lv);
        float rr = slapy2f(gg, 1.f);
        gg = rl(d0, mq) - pp + e_lv * frcp(gg + copysignf(rr, gg));
        float ss_ = 1.f, cc_ = 1.f;
        pp = 0.f;
#pragma unroll
        for (int i = 14; i >= 0; i--) {
          if (i <= mq - 1 && i >= l) {   // wave-uniform guard; i compile-time
            float e_i = eArr[i], d_i = dArr[i], d_i1 = dArr[i + 1];
            float ff = ss_ * e_i, bb = cc_ * e_i;
            slartgf(gg, ff, &cc_, &ss_, &rr);
            if (i != mq - 1) { if (lane == i + 1) ereg = rr; }
            gg = d_i1 - pp;
            rr = (d_i - gg) * ss_ + 2.f * cc_ * bb;
            pp = ss_ * rr;
            float dnew = gg + pp;
            if (lane == i + 1) dreg = dnew;
            if (lane == i) dsh = dnew;
            gg = cc_ * rr - bb;
            float z1 = zz[i + 1], z0v = zz[i];   // QL (slasr 'B', (c,-s))
            zz[i + 1] = cc_ * z1 + ss_ * z0v;
            zz[i] = -ss_ * z1 + cc_ * z0v;
          }
        }
        float dlv = rl(d0, l) - pp;
        if (lane == l) { dreg = dlv; ereg = gg; }
        if (lane == l - 1) dsh = dlv;
      }
    } else {
      // ---- QR ----
      for (;;) {
        bool cj = (lane < 15) && ((ereg * ereg) <= eps2 * fabsf(dreg) * fabsf(dsh) + safmin);
        int mq;
        if (l != lend) {
          unsigned long long bb2 = __ballot(cj) & ((1ull << l) - 1ull) & ~((1ull << lend) - 1ull);
          mq = bb2 ? (63 - __clzll(bb2) + 1) : lend;
        } else mq = lend;
        if (mq > lend) { if (lane == mq - 1) ereg = 0.f; }
        if (mq == l) { l--; if (l >= lend) continue; break; }
        if (mq == l - 1) {
          float4 ev = slaev2f(rl(dreg, l - 1), rl(ereg, l - 1), rl(dreg, l));
          float rt1 = ev.x, rt2 = ev.y, cc = ev.z, ss = ev.w;
#pragma unroll
          for (int k = 0; k < 15; k++) if (k == l - 1) {
            float z1 = zz[k + 1], z0v = zz[k];
            zz[k + 1] = cc * z1 - ss * z0v;
            zz[k] = ss * z1 + cc * z0v;
          }
          if (lane == l - 1) { dreg = rt1; ereg = 0.f; dsh = rt2; }
          if (lane == l) dreg = rt2;
          if (lane == l - 2) dsh = rt1;
          l -= 2; if (l >= lend) continue; break;
        }
        if (jtot == nmaxit) break;
        jtot++;
        float d0 = dreg, e0 = ereg;
        float dArr[16], eArr[15];
#pragma unroll
        for (int r = 0; r < 16; r++) dArr[r] = rl(d0, r);
#pragma unroll
        for (int r = 0; r < 15; r++) eArr[r] = rl(e0, r);
        float pp = rl(d0, l);
        float e_lm1 = rl(e0, l - 1);
        float gg = (rl(d0, l - 1) - pp) * 0.5f * frcp(e_lm1);
        float rr = slapy2f(gg, 1.f);
        gg = rl(d0, mq) - pp + e_lm1 * frcp(gg + copysignf(rr, gg));
        float ss_ = 1.f, cc_ = 1.f;
        pp = 0.f;
#pragma unroll
        for (int i = 0; i <= 14; i++) {
          if (i >= mq && i <= l - 1) {   // wave-uniform guard; i compile-time
            float e_i = eArr[i], d_i = dArr[i], d_i1 = dArr[i + 1];
            float ff = ss_ * e_i, bb = cc_ * e_i;
            slartgf(gg, ff, &cc_, &ss_, &rr);
            if (i != mq) { if (lane == i - 1) ereg = rr; }
            gg = d_i - pp;
            rr = (d_i1 - gg) * ss_ + 2.f * cc_ * bb;
            pp = ss_ * rr;
            float dnew = gg + pp;
            if (lane == i) dreg = dnew;
            if (lane == i - 1) dsh = dnew;
            gg = cc_ * rr - bb;
            float z1 = zz[i + 1], z0v = zz[i];   // QR (slasr 'F', (c,s))
            zz[i + 1] = cc_ * z1 - ss_ * z0v;
            zz[i] = ss_ * z1 + cc_ * z0v;
          }
        }
        float dlv = rl(d0, l) - pp;
        if (lane == l) dreg = dlv;
        if (lane == l - 1) { ereg = gg; dsh = dlv; }
      }
    }
  }

  // ---- outputs ----
  float mx = rl(dreg, 0);
  int k = 0;
#pragma unroll
  for (int j = 1; j < 16; j++) {
    float dj = rl(dreg, j);
    if (dj > mx) { mx = dj; k = j; }
  }
  float ratio = mx / trace;
  float act = 1.f / (1.f + expf(-(ratio - biasv)));
  float zk = zz[0];
#pragma unroll
  for (int j = 1; j < 16; j++) zk = (k == j) ? zz[j] : zk;
  if (lane < 16) out[512 + bo * 16 + lane] = zk;
  if (lane == 0) out[bo] = act;
}

extern "C" void kernel_launch(void* const* d_in, const int* in_sizes, int n_in,
                              void* d_out, int out_size, void* d_ws, size_t ws_size,
                              hipStream_t stream) {
  const float* in = (const float*)d_in[0];
  const float* w = (const float*)d_in[1];
  const float* bias = (const float*)d_in[2];
  float* out = (float*)d_out;
  float* Tmom = (float*)d_ws;                      // 512*256 floats = 512 KB
  float* ws2 = (float*)d_ws + 512 * 256;           // 512*320 floats = 640 KB

  moments_kernel<<<B_ * L_, 256, 0, stream>>>(in, Tmom);
  gram_sytd2_kernel<<<B_ * O_, 64, 0, stream>>>(Tmom, w, ws2);
  steqr_kernel<<<B_ * O_, 64, 0, stream>>>(ws2, bias, out);
}

// Round 9
// 134.351 us; speedup vs baseline: 1.0127x; 1.0052x over previous
//
#include <hip/hip_runtime.h>

#define B_ 16
#define L_ 32
#define O_ 32
#define M_ 256
#define CH_ 544   // L*(P+1)

// ---------- cross-lane helpers ----------

__device__ __forceinline__ float rl(float v, int lane) {
  return __int_as_float(__builtin_amdgcn_readlane(__float_as_int(v), lane));
}

__device__ __forceinline__ float sum16_rl(float v) {
  float s = rl(v, 0);
#pragma unroll
  for (int j = 1; j < 16; j++) s += rl(v, j);
  return s;
}

__device__ __forceinline__ float frcp(float x) { return __builtin_amdgcn_rcpf(x); }
__device__ __forceinline__ float frsq(float x) { return __builtin_amdgcn_rsqf(x); }

// ---------- LAPACK helper transcriptions (f32) ----------

__device__ __forceinline__ float slapy2f(float x, float y) {
  float xa = fabsf(x), ya = fabsf(y);
  float w = fmaxf(xa, ya), z = fminf(xa, ya);
  float q = z * frcp(w);
  float res = w * sqrtf(1.f + q * q);
  return (z == 0.f) ? w : res;
}

// LAPACK >= 3.10 slartg convention; single-rsq, branchless.
__device__ __forceinline__ void slartgf(float f, float g, float* c, float* s, float* r) {
  float t = f * f + g * g;
  float inv = frsq(t);
  float d = t * inv;
  float cg_ = fabsf(f) * inv;
  float rg = copysignf(d, f);
  float sg = g * copysignf(inv, f);
  bool g0 = (g == 0.f), f0 = (f == 0.f);
  *c = g0 ? 1.f : (f0 ? 0.f : cg_);
  *s = g0 ? 0.f : (f0 ? copysignf(1.f, g) : sg);
  *r = g0 ? f : (f0 ? fabsf(g) : rg);
}

// returns (rt1, rt2, cs1, sn1); noinline: 1 code copy (icache)
__device__ __noinline__ float4 slaev2f(float a, float b, float c) {
  float sm = a + c, df = a - c;
  float adf = fabsf(df);
  float tb = b + b;
  float ab = fabsf(tb);
  float acmx, acmn;
  if (fabsf(a) > fabsf(c)) { acmx = a; acmn = c; } else { acmx = c; acmn = a; }
  float rt;
  if (adf > ab) { float q = ab / adf; rt = adf * sqrtf(1.f + q * q); }
  else if (adf < ab) { float q = adf / ab; rt = ab * sqrtf(1.f + q * q); }
  else rt = ab * sqrtf(2.f);
  float rt1, rt2;
  int sgn1;
  if (sm < 0.f) { rt1 = 0.5f * (sm - rt); sgn1 = -1; rt2 = (acmx / rt1) * acmn - (b / rt1) * b; }
  else if (sm > 0.f) { rt1 = 0.5f * (sm + rt); sgn1 = 1; rt2 = (acmx / rt1) * acmn - (b / rt1) * b; }
  else { rt1 = 0.5f * rt; rt2 = -0.5f * rt; sgn1 = 1; }
  float cs; int sgn2;
  if (df >= 0.f) { cs = df + rt; sgn2 = 1; } else { cs = df - rt; sgn2 = -1; }
  float acs = fabsf(cs), c1, s1;
  if (acs > ab) { float ct = -tb / cs; s1 = 1.f / sqrtf(1.f + ct * ct); c1 = ct * s1; }
  else if (ab == 0.f) { c1 = 1.f; s1 = 0.f; }
  else { float tn = -cs / tb; c1 = 1.f / sqrtf(1.f + tn * tn); s1 = tn * c1; }
  if (sgn1 == sgn2) { float tn = c1; c1 = -s1; s1 = tn; }
  return make_float4(rt1, rt2, c1, s1);
}

// ---------- Kernel 1: weighted pose second moments (COALESCED pose loads) ----------
// lane = (row16 = lane>>2, quarter = lane&3): each row's 16 poses are exactly one
// 64B-aligned line (544*4 and l*64 are 64B multiples) -> 16 lines per wave-load
// instead of 64. Act round-trips LDS so u = a*p is bitwise identical to before.
__global__ __launch_bounds__(256) void moments_kernel(const float* __restrict__ in,
                                                      float* __restrict__ Tmom) {
  int bl = blockIdx.x;
  int b = bl >> 5, l = bl & 31;
  int t = threadIdx.x;
  int w = t >> 6, lane = t & 63;
  __shared__ __align__(16) float ut[4][16][68];
  __shared__ float ash[4][64];
  __shared__ float red[4][16][16];
  const float* base = in + (size_t)b * (M_ * CH_);
  int mrow = lane >> 2, q = lane & 3;
  int row0 = w * 64;
  // issue all global loads upfront (4 coalesced pose quads + 1 scattered act)
  float4 p0 = *(const float4*)(base + (size_t)(row0 + 0 * 16 + mrow) * CH_ + l * 16 + q * 4);
  float4 p1 = *(const float4*)(base + (size_t)(row0 + 1 * 16 + mrow) * CH_ + l * 16 + q * 4);
  float4 p2 = *(const float4*)(base + (size_t)(row0 + 2 * 16 + mrow) * CH_ + l * 16 + q * 4);
  float4 p3 = *(const float4*)(base + (size_t)(row0 + 3 * 16 + mrow) * CH_ + l * 16 + q * 4);
  float a = base[(size_t)(row0 + lane) * CH_ + 512 + l];
  ash[w][lane] = a;
  asm volatile("" ::: "memory");   // single-wave private region; DS pipe in-order
  {
    float aa0 = ash[w][0 * 16 + mrow];
    float aa1 = ash[w][1 * 16 + mrow];
    float aa2 = ash[w][2 * 16 + mrow];
    float aa3 = ash[w][3 * 16 + mrow];
    float (*u)[68] = ut[w];
    u[q * 4 + 0][0 * 16 + mrow] = aa0 * p0.x;
    u[q * 4 + 1][0 * 16 + mrow] = aa0 * p0.y;
    u[q * 4 + 2][0 * 16 + mrow] = aa0 * p0.z;
    u[q * 4 + 3][0 * 16 + mrow] = aa0 * p0.w;
    u[q * 4 + 0][1 * 16 + mrow] = aa1 * p1.x;
    u[q * 4 + 1][1 * 16 + mrow] = aa1 * p1.y;
    u[q * 4 + 2][1 * 16 + mrow] = aa1 * p1.z;
    u[q * 4 + 3][1 * 16 + mrow] = aa1 * p1.w;
    u[q * 4 + 0][2 * 16 + mrow] = aa2 * p2.x;
    u[q * 4 + 1][2 * 16 + mrow] = aa2 * p2.y;
    u[q * 4 + 2][2 * 16 + mrow] = aa2 * p2.z;
    u[q * 4 + 3][2 * 16 + mrow] = aa2 * p2.w;
    u[q * 4 + 0][3 * 16 + mrow] = aa3 * p3.x;
    u[q * 4 + 1][3 * 16 + mrow] = aa3 * p3.y;
    u[q * 4 + 2][3 * 16 + mrow] = aa3 * p3.z;
    u[q * 4 + 3][3 * 16 + mrow] = aa3 * p3.w;
  }
  asm volatile("" ::: "memory");
  int c = lane & 15, r0 = lane >> 4;
  float (*u)[68] = ut[w];
  float acc0 = 0.f, acc1 = 0.f, acc2 = 0.f, acc3 = 0.f;
#pragma unroll
  for (int m4 = 0; m4 < 64; m4 += 4) {
    float4 cv = *(const float4*)&u[c][m4];
    float4 a0 = *(const float4*)&u[r0][m4];
    float4 a1 = *(const float4*)&u[r0 + 4][m4];
    float4 a2 = *(const float4*)&u[r0 + 8][m4];
    float4 a3 = *(const float4*)&u[r0 + 12][m4];
    acc0 += a0.x * cv.x + a0.y * cv.y + a0.z * cv.z + a0.w * cv.w;
    acc1 += a1.x * cv.x + a1.y * cv.y + a1.z * cv.z + a1.w * cv.w;
    acc2 += a2.x * cv.x + a2.y * cv.y + a2.z * cv.z + a2.w * cv.w;
    acc3 += a3.x * cv.x + a3.y * cv.y + a3.z * cv.z + a3.w * cv.w;
  }
  red[w][r0][c] = acc0;
  red[w][r0 + 4][c] = acc1;
  red[w][r0 + 8][c] = acc2;
  red[w][r0 + 12][c] = acc3;
  __syncthreads();
  int rr_ = t >> 4, cc_ = t & 15;
  float s = (red[0][rr_][cc_] + red[1][rr_][cc_]) + (red[2][rr_][cc_] + red[3][rr_][cc_]);
  Tmom[bl * 256 + t] = s;
}

// ---------- Kernel 2: gram + sytd2 + Q-form + steqr (merged, R4 structure) ----------
__global__ __launch_bounds__(64) void gram_eig_kernel(const float* __restrict__ Tmom,
                                                      const float* __restrict__ Wt,
                                                      const float* __restrict__ bias,
                                                      float* __restrict__ out) {
  int bo = blockIdx.x;
  int b = bo >> 5, o = bo & 31;
  int lane = threadIdx.x;

  __shared__ __align__(16) float4 Wall4[128];
  __shared__ __align__(16) float4 Tsh4[4 * 18];
  __shared__ float A[16][17];
  __shared__ __align__(16) float Zt[16][16];

  float biasv = bias[o];

  // ---- stage W (single wave: DS in-order, no barrier) ----
  const float4* Wt4 = (const float4*)Wt;
#pragma unroll
  for (int k = 0; k < 2; k++) {
    int idx = lane + 64 * k;
    int l = idx >> 2, part = idx & 3;
    Wall4[idx] = Wt4[(l * 32 + o) * 4 + part];
  }
  asm volatile("" ::: "memory");

  // ---- gram (single-copy T, depth-4 prefetch, barrier-free) ----
  int p = lane >> 2;
  int i_ = p >> 2, k_ = p & 3;
  int i2 = lane & 3;
  float gx = 0.f, gy = 0.f, gz = 0.f, gw = 0.f;
  const float4* T4 = (const float4*)(Tmom + (size_t)(b * 32) * 256);
  const float* WallF = (const float*)Wall4;
  float4 t0 = T4[0 * 64 + lane], t1 = T4[1 * 64 + lane];
  float4 t2 = T4[2 * 64 + lane], t3 = T4[3 * 64 + lane];
  for (int l = 0; l < 32; l++) {
    Tsh4[(lane >> 4) * 18 + (lane & 15)] = t0;
    asm volatile("" ::: "memory");
    t0 = t1; t1 = t2; t2 = t3;
    if (l + 4 < 32) t3 = T4[(l + 4) * 64 + lane];
    float4 wq0 = Wall4[l * 4 + 0], wq1 = Wall4[l * 4 + 1];
    float4 wq2 = Wall4[l * 4 + 2], wq3 = Wall4[l * 4 + 3];
#pragma unroll
    for (int jj = 0; jj < 4; jj++) {
      float4 trow = Tsh4[i_ * 18 + jj * 4 + i2];
      float ux = trow.x * wq0.x + trow.y * wq1.x + trow.z * wq2.x + trow.w * wq3.x;
      float uy = trow.x * wq0.y + trow.y * wq1.y + trow.z * wq2.y + trow.w * wq3.y;
      float uz = trow.x * wq0.z + trow.y * wq1.z + trow.z * wq2.z + trow.w * wq3.z;
      float uw = trow.x * wq0.w + trow.y * wq1.w + trow.z * wq2.w + trow.w * wq3.w;
      float wk = WallF[l * 16 + jj * 4 + k_];
      gx += wk * ux; gy += wk * uy; gz += wk * uz; gw += wk * uw;
    }
    asm volatile("" ::: "memory");
  }
  {
    int q0 = i2 * 4;
    A[p][q0 + 0] = gx; A[p][q0 + 1] = gy; A[p][q0 + 2] = gz; A[p][q0 + 3] = gw;
  }
  asm volatile("" ::: "memory");

  // ---- load A columns into registers: lane c holds a[r] = A[r][c] ----
  int c16 = lane & 15;
  float a[16];
#pragma unroll
  for (int r = 0; r < 16; r++) a[r] = A[r][c16];

  float trace;
  {
    float diag = 0.f;
#pragma unroll
    for (int r = 0; r < 16; r++) if (c16 == r) diag = a[r];
    trace = sum16_rl((lane < 16) ? diag : 0.f);
  }

  // ---- ssytd2 (lower), register-resident ----
  float dreg = 0.f, ereg = 0.f, taureg = 0.f;
  float hv[14];
#pragma unroll
  for (int i = 0; i < 15; i++) {
    float cn = 0.f;
#pragma unroll
    for (int r = i + 2; r < 16; r++) cn += a[r] * a[r];
    float xn2 = rl(cn, i);
    float alpha = rl(a[i + 1], i);
    float taui = 0.f;
    float vc = 0.f;
    if (xn2 == 0.f) {
      if (lane == i) ereg = alpha;
    } else {
      float xnorm = sqrtf(xn2);
      float beta = -copysignf(slapy2f(alpha, xnorm), alpha);
      taui = (beta - alpha) / beta;
      float rs = 1.f / (alpha - beta);
      if (lane == i) ereg = beta;
      vc = (lane == i + 1) ? 1.f : ((lane >= i + 2 && lane < 16) ? a[i] * rs : 0.f);
      float vb[16];
#pragma unroll
      for (int r = i + 1; r < 16; r++) vb[r] = rl(vc, r);
      float acc = 0.f;
#pragma unroll
      for (int r = i + 1; r < 16; r++) acc += a[r] * vb[r];
      float wc = (lane >= i + 1 && lane < 16) ? taui * acc : 0.f;
      float wb[16];
#pragma unroll
      for (int r = i + 1; r < 16; r++) wb[r] = rl(wc, r);
      float dot = 0.f;
#pragma unroll
      for (int r = i + 1; r < 16; r++) dot += vb[r] * wb[r];
      float alph2 = -0.5f * taui * dot;
      wc += alph2 * vc;
#pragma unroll
      for (int r = i + 1; r < 16; r++) wb[r] += alph2 * vb[r];
#pragma unroll
      for (int r = i + 1; r < 16; r++) a[r] -= vb[r] * wc + wb[r] * vc;
    }
    if (i < 14) hv[i] = vc;
    if (lane == i) taureg = taui;
  }
#pragma unroll
  for (int r = 0; r < 16; r++) if (c16 == r) dreg = a[r];
  if (lane >= 16) dreg = 0.f;

  // ---- form Q = H(1)..H(14); lane = column, rows in registers ----
  float z[16];
#pragma unroll
  for (int r = 0; r < 16; r++) z[r] = (lane == r) ? 1.f : 0.f;
#pragma unroll
  for (int i = 13; i >= 0; i--) {
    float taui = rl(taureg, i);
    if (taui != 0.f) {
      float vbq[16];
      float s = 0.f;
#pragma unroll
      for (int r = i + 1; r < 16; r++) { vbq[r] = rl(hv[i], r); s += vbq[r] * z[r]; }
      s *= taui;
#pragma unroll
      for (int r = i + 1; r < 16; r++) z[r] -= vbq[r] * s;
    }
  }
  if (lane < 16) {
    float4* zt4 = (float4*)&Zt[lane][0];      // Zt[col][row]
    zt4[0] = make_float4(z[0], z[1], z[2], z[3]);
    zt4[1] = make_float4(z[4], z[5], z[6], z[7]);
    zt4[2] = make_float4(z[8], z[9], z[10], z[11]);
    zt4[3] = make_float4(z[12], z[13], z[14], z[15]);
  }
  asm volatile("" ::: "memory");

  // ---- transpose handoff: zz[col] = Z[lane][col], register-resident ----
  float zz[16];
#pragma unroll
  for (int k2 = 0; k2 < 16; k2++) zz[k2] = (lane < 16) ? Zt[k2][c16] : 0.f;

  // ---- ssteqr; d,e lane-resident; Z in registers; hoisted snapshot broadcasts ----
  const float eps = 5.9604645e-08f;
  const float eps2 = eps * eps;
  const float safmin = 1.17549435e-38f;
  int l1 = 0, jtot = 0;
  const int nmaxit = 480;
  float dsh = __shfl(dreg, (lane + 1) & 63, 64);

  while (l1 < 16) {
    if (l1 > 0) { if (lane == l1 - 1) ereg = 0.f; }
    bool co = (lane < 15) &&
              ((ereg == 0.f) ||
               (fabsf(ereg) <= __builtin_amdgcn_sqrtf(fabsf(dreg)) *
                                   __builtin_amdgcn_sqrtf(fabsf(dsh)) * eps));
    unsigned long long bm = __ballot(co) & ~((1ull << l1) - 1ull);
    int m = bm ? (__ffsll(bm) - 1) : 15;
    if (m < 15) { if (lane == m) ereg = 0.f; }
    int l = l1, lend = m;
    l1 = m + 1;
    if (lend == l) continue;
    {
      float dl = rl(dreg, l), dle = rl(dreg, lend);
      if (fabsf(dle) < fabsf(dl)) { int tq = l; l = lend; lend = tq; }
    }

    if (lend > l) {
      // ---- QL ----
      for (;;) {
        bool cj = (lane < 15) && ((ereg * ereg) <= eps2 * fabsf(dreg) * fabsf(dsh) + safmin);
        int mq;
        if (l != lend) {
          unsigned long long bb2 = __ballot(cj) & ((1ull << lend) - 1ull) & ~((1ull << l) - 1ull);
          mq = bb2 ? (__ffsll(bb2) - 1) : lend;
        } else mq = lend;
        if (mq < lend) { if (lane == mq) ereg = 0.f; }
        if (mq == l) { l++; if (l <= lend) continue; break; }
        if (mq == l + 1) {
          float4 ev = slaev2f(rl(dreg, l), rl(ereg, l), rl(dreg, l + 1));
          float rt1 = ev.x, rt2 = ev.y, cc = ev.z, ss = ev.w;
#pragma unroll
          for (int k = 0; k < 15; k++) if (k == l) {
            float z1 = zz[k + 1], z0v = zz[k];
            zz[k + 1] = cc * z1 - ss * z0v;
            zz[k] = ss * z1 + cc * z0v;
          }
          if (lane == l) { dreg = rt1; ereg = 0.f; dsh = rt2; }
          if (lane == l + 1) dreg = rt2;
          if (lane == l - 1) dsh = rt1;
          l += 2; if (l <= lend) continue; break;
        }
        if (jtot == nmaxit) break;
        jtot++;
        float d0 = dreg, e0 = ereg;   // pre-sweep snapshots
        float dArr[16], eArr[15];
#pragma unroll
        for (int r = 0; r < 16; r++) dArr[r] = rl(d0, r);
#pragma unroll
        for (int r = 0; r < 15; r++) eArr[r] = rl(e0, r);
        float pp = rl(d0, l);
        float e_lv = rl(e0, l);
        float gg = (rl(d0, l + 1) - pp) * 0.5f * frcp(e_lv);
        float rr = slapy2f(gg, 1.f);
        gg = rl(d0, mq) - pp + e_lv * frcp(gg + copysignf(rr, gg));
        float ss_ = 1.f, cc_ = 1.f;
        pp = 0.f;
#pragma unroll
        for (int i = 14; i >= 0; i--) {
          if (i <= mq - 1 && i >= l) {   // wave-uniform guard; i compile-time
            float e_i = eArr[i], d_i = dArr[i], d_i1 = dArr[i + 1];
            float ff = ss_ * e_i, bb = cc_ * e_i;
            slartgf(gg, ff, &cc_, &ss_, &rr);
            if (i != mq - 1) { if (lane == i + 1) ereg = rr; }
            gg = d_i1 - pp;
            rr = (d_i - gg) * ss_ + 2.f * cc_ * bb;
            pp = ss_ * rr;
            float dnew = gg + pp;
            if (lane == i + 1) dreg = dnew;
            if (lane == i) dsh = dnew;
            gg = cc_ * rr - bb;
            float z1 = zz[i + 1], z0v = zz[i];   // QL (slasr 'B', (c,-s))
            zz[i + 1] = cc_ * z1 + ss_ * z0v;
            zz[i] = -ss_ * z1 + cc_ * z0v;
          }
        }
        float dlv = rl(d0, l) - pp;
        if (lane == l) { dreg = dlv; ereg = gg; }
        if (lane == l - 1) dsh = dlv;
      }
    } else {
      // ---- QR ----
      for (;;) {
        bool cj = (lane < 15) && ((ereg * ereg) <= eps2 * fabsf(dreg) * fabsf(dsh) + safmin);
        int mq;
        if (l != lend) {
          unsigned long long bb2 = __ballot(cj) & ((1ull << l) - 1ull) & ~((1ull << lend) - 1ull);
          mq = bb2 ? (63 - __clzll(bb2) + 1) : lend;
        } else mq = lend;
        if (mq > lend) { if (lane == mq - 1) ereg = 0.f; }
        if (mq == l) { l--; if (l >= lend) continue; break; }
        if (mq == l - 1) {
          float4 ev = slaev2f(rl(dreg, l - 1), rl(ereg, l - 1), rl(dreg, l));
          float rt1 = ev.x, rt2 = ev.y, cc = ev.z, ss = ev.w;
#pragma unroll
          for (int k = 0; k < 15; k++) if (k == l - 1) {
            float z1 = zz[k + 1], z0v = zz[k];
            zz[k + 1] = cc * z1 - ss * z0v;
            zz[k] = ss * z1 + cc * z0v;
          }
          if (lane == l - 1) { dreg = rt1; ereg = 0.f; dsh = rt2; }
          if (lane == l) dreg = rt2;
          if (lane == l - 2) dsh = rt1;
          l -= 2; if (l >= lend) continue; break;
        }
        if (jtot == nmaxit) break;
        jtot++;
        float d0 = dreg, e0 = ereg;
        float dArr[16], eArr[15];
#pragma unroll
        for (int r = 0; r < 16; r++) dArr[r] = rl(d0, r);
#pragma unroll
        for (int r = 0; r < 15; r++) eArr[r] = rl(e0, r);
        float pp = rl(d0, l);
        float e_lm1 = rl(e0, l - 1);
        float gg = (rl(d0, l - 1) - pp) * 0.5f * frcp(e_lm1);
        float rr = slapy2f(gg, 1.f);
        gg = rl(d0, mq) - pp + e_lm1 * frcp(gg + copysignf(rr, gg));
        float ss_ = 1.f, cc_ = 1.f;
        pp = 0.f;
#pragma unroll
        for (int i = 0; i <= 14; i++) {
          if (i >= mq && i <= l - 1) {   // wave-uniform guard; i compile-time
            float e_i = eArr[i], d_i = dArr[i], d_i1 = dArr[i + 1];
            float ff = ss_ * e_i, bb = cc_ * e_i;
            slartgf(gg, ff, &cc_, &ss_, &rr);
            if (i != mq) { if (lane == i - 1) ereg = rr; }
            gg = d_i - pp;
            rr = (d_i1 - gg) * ss_ + 2.f * cc_ * bb;
            pp = ss_ * rr;
            float dnew = gg + pp;
            if (lane == i) dreg = dnew;
            if (lane == i - 1) dsh = dnew;
            gg = cc_ * rr - bb;
            float z1 = zz[i + 1], z0v = zz[i];   // QR (slasr 'F', (c,s))
            zz[i + 1] = cc_ * z1 - ss_ * z0v;
            zz[i] = ss_ * z1 + cc_ * z0v;
          }
        }
        float dlv = rl(d0, l) - pp;
        if (lane == l) dreg = dlv;
        if (lane == l - 1) { ereg = gg; dsh = dlv; }
      }
    }
  }

  // ---- outputs ----
  float mx = rl(dreg, 0);
  int k = 0;
#pragma unroll
  for (int j = 1; j < 16; j++) {
    float dj = rl(dreg, j);
    if (dj > mx) { mx = dj; k = j; }
  }
  float ratio = mx / trace;
  float act = 1.f / (1.f + expf(-(ratio - biasv)));
  float zk = zz[0];
#pragma unroll
  for (int j = 1; j < 16; j++) zk = (k == j) ? zz[j] : zk;
  if (lane < 16) out[512 + bo * 16 + lane] = zk;
  if (lane == 0) out[bo] = act;
}

extern "C" void kernel_launch(void* const* d_in, const int* in_sizes, int n_in,
                              void* d_out, int out_size, void* d_ws, size_t ws_size,
                              hipStream_t stream) {
  const float* in = (const float*)d_in[0];
  const float* w = (const float*)d_in[1];
  const float* bias = (const float*)d_in[2];
  float* out = (float*)d_out;
  float* Tmom = (float*)d_ws;  // 512 * 256 floats = 512 KB scratch

  moments_kernel<<<B_ * L_, 256, 0, stream>>>(in, Tmom);
  gram_eig_kernel<<<B_ * O_, 64, 0, stream>>>(Tmom, w, bias, out);
}